// Round 12
// baseline (47.135 us; speedup 1.0000x reference)
//
#include <hip/hip_runtime.h>

// R8/R11 structure, ONE change: prefetch of row j+2 issued AFTER the barrier.
// The per-row __syncthreads emits s_waitcnt vmcnt(0); with the prefetch issued
// before it (R8), the block stalled on HBM latency at every barrier. Issued
// after, the load is consumed by next iteration's ds_write staging (natural
// vmcnt dependency), overlapping phase3 + store + next phase2.
#define D_LEN 1024
#define K_LEN 8
#define NS    10
#define LCC   516
#define GRID  2048

typedef float floatx4 __attribute__((ext_vector_type(4)));

__global__ __launch_bounds__(256) void wavecore_kernel(
    const float* __restrict__ x,
    const float* __restrict__ dec_lo, const float* __restrict__ dec_hi,
    const float* __restrict__ rec_lo, const float* __restrict__ rec_hi,
    const float* __restrict__ sp_c,   const int* __restrict__ sp_i,
    float* __restrict__ out, int J)
{
    __shared__ __align__(16) float  sx[2][D_LEN];
    __shared__ __align__(16) float2 st[2][512];

    const int tid = threadIdx.x;

    float fdl[K_LEN], fdh[K_LEN], frl[K_LEN], frh[K_LEN];
#pragma unroll
    for (int k = 0; k < K_LEN; ++k) {
        fdl[k] = dec_lo[k]; fdh[k] = dec_hi[k];
        frl[k] = rec_lo[k]; frh[k] = rec_hi[k];
    }

    // ---- inline delta: dq = rec(sparse-only pairs) for this thread's quad ----
    float dq0, dq1, dq2, dq3;
    {
        float4 z; z.x = 0.f; z.y = 0.f; z.z = 0.f; z.w = 0.f;
        ((float4*)st[0])[tid] = z;
        __syncthreads();
        if (tid < NS) {
            const int   s = sp_i[tid];
            const float v = sp_c[tid];
            if (s < 512)       st[0][s].x = v;        // distinct indices, no race
            else if (s >= LCC) st[0][s - LCC].y = v;  // lo c in [512,516) unused
        }
        __syncthreads();
        if (tid >= 2) {
            const float4 qa = ((const float4*)st[0])[tid - 2];
            const float4 qb = ((const float4*)st[0])[tid - 1];
            const float4 qc = ((const float4*)st[0])[tid];
            const float p0l = qa.z, p0h = qa.w;
            const float p1l = qb.x, p1h = qb.y;
            const float p2l = qb.z, p2h = qb.w;
            const float p3l = qc.x, p3h = qc.y;
            const float p4l = qc.z, p4h = qc.w;
            dq0 = p0l*frl[1] + p0h*frh[1] + p1l*frl[3] + p1h*frh[3]
                + p2l*frl[5] + p2h*frh[5] + p3l*frl[7] + p3h*frh[7];
            dq1 = p0l*frl[0] + p0h*frh[0] + p1l*frl[2] + p1h*frh[2]
                + p2l*frl[4] + p2h*frh[4] + p3l*frl[6] + p3h*frh[6];
            dq2 = p1l*frl[1] + p1h*frh[1] + p2l*frl[3] + p2h*frh[3]
                + p3l*frl[5] + p3h*frh[5] + p4l*frl[7] + p4h*frh[7];
            dq3 = p1l*frl[0] + p1h*frh[0] + p2l*frl[2] + p2h*frh[2]
                + p3l*frl[4] + p3h*frh[4] + p4l*frl[6] + p4h*frh[6];
        } else {
            float acc[4];
#pragma unroll
            for (int j = 0; j < 4; ++j) {
                const int t  = 4 * tid + j;
                const int k0 = ((j & 1) ^ 1);
                float a = 0.f;
#pragma unroll
                for (int i = 0; i < 4; ++i) {
                    const int k = k0 + 2 * i;
                    int m = t + k - 7;
                    m = (m < 0) ? -m : m;
                    const float2 pv = st[0][m >> 1];
                    a = fmaf(pv.x, frl[k], a);
                    a = fmaf(pv.y, frh[k], a);
                }
                acc[j] = a;
            }
            dq0 = acc[0]; dq1 = acc[1]; dq2 = acc[2]; dq3 = acc[3];
        }
        __syncthreads();   // st[0] free for reuse
    }

    // ---- prologue: row0 -> regs+sx[0]; row1 -> xn ----
    size_t off = (size_t)blockIdx.x * D_LEN + 4 * (size_t)tid;
    const size_t rstride = (size_t)GRID * D_LEN;
    float4 xv = *(const float4*)(x + off);
    ((float4*)sx[0])[tid] = xv;
    float4 xn = *(const float4*)(x + off + rstride);   // J >= 2
    __syncthreads();                                   // sx[0] ready

    int cur = 0, sb = 0;
#pragma unroll 1
    for (int j = 0; j < J; ++j) {
        // ---- phase 2 on sx[cur] + own regs -> st[sb] ----
        const float* sxc = sx[cur];
        float lo0 = 0.f, hi0 = 0.f, lo1 = 0.f, hi1 = 0.f;
        if (tid >= 2) {
            const float4 wa = ((const float4*)sxc)[tid - 2];
            const float4 wb = ((const float4*)sxc)[tid - 1];
            const float w[12] = { wa.x, wa.y, wa.z, wa.w,
                                  wb.x, wb.y, wb.z, wb.w,
                                  xv.x, xv.y, xv.z, xv.w };
#pragma unroll
            for (int jj = 0; jj < K_LEN; ++jj) {
                const float v0 = w[8  - jj];
                const float v1 = w[10 - jj];
                lo0 = fmaf(v0, fdl[jj], lo0);
                hi0 = fmaf(v0, fdh[jj], hi0);
                lo1 = fmaf(v1, fdl[jj], lo1);
                hi1 = fmaf(v1, fdh[jj], hi1);
            }
        } else {
#pragma unroll
            for (int q = 0; q < 2; ++q) {
                const int c = 2 * tid + q;
                float aL = 0.f, aH = 0.f;
#pragma unroll
                for (int jj = 0; jj < K_LEN; ++jj) {
                    int m = 2 * c - jj;
                    m = (m < 0) ? -m : m;
                    const float v = sxc[m];
                    aL = fmaf(v, fdl[jj], aL);
                    aH = fmaf(v, fdh[jj], aH);
                }
                if (q == 0) { lo0 = aL; hi0 = aH; }
                else        { lo1 = aL; hi1 = aH; }
            }
        }
        {
            float4 pr; pr.x = lo0; pr.y = hi0; pr.z = lo1; pr.w = hi1;
            ((float4*)st[sb])[tid] = pr;
        }
        // stage row j+1 into alternate x-buffer (vmcnt-waits on its prefetch)
        if (j + 1 < J) ((float4*)sx[cur ^ 1])[tid] = xn;
        __syncthreads();   // the ONE barrier: st[sb] + sx[cur^1] ready

        // ---- prefetch row j+2 AFTER the barrier: overlaps phase3 + store +
        //      next phase2; never drained by a barrier before consumption ----
        float4 xn2;
        if (j + 2 < J) xn2 = *(const float4*)(x + off + 2 * rstride);

        // ---- phase 3 from st[sb] + own pair regs; nt store ----
        float res0, res1, res2, res3;
        if (tid >= 2) {
            const float4 qa = ((const float4*)st[sb])[tid - 2];
            const float4 qb = ((const float4*)st[sb])[tid - 1];
            const float p0l = qa.z, p0h = qa.w;
            const float p1l = qb.x, p1h = qb.y;
            const float p2l = qb.z, p2h = qb.w;
            const float p3l = lo0,  p3h = hi0;
            const float p4l = lo1,  p4h = hi1;
            res0 = p0l*frl[1] + p0h*frh[1] + p1l*frl[3] + p1h*frh[3]
                 + p2l*frl[5] + p2h*frh[5] + p3l*frl[7] + p3h*frh[7];
            res1 = p0l*frl[0] + p0h*frh[0] + p1l*frl[2] + p1h*frh[2]
                 + p2l*frl[4] + p2h*frh[4] + p3l*frl[6] + p3h*frh[6];
            res2 = p1l*frl[1] + p1h*frh[1] + p2l*frl[3] + p2h*frh[3]
                 + p3l*frl[5] + p3h*frh[5] + p4l*frl[7] + p4h*frh[7];
            res3 = p1l*frl[0] + p1h*frh[0] + p2l*frl[2] + p2h*frh[2]
                 + p3l*frl[4] + p3h*frh[4] + p4l*frl[6] + p4h*frh[6];
        } else {
            float acc[4];
#pragma unroll
            for (int jj = 0; jj < 4; ++jj) {
                const int t  = 4 * tid + jj;
                const int k0 = ((jj & 1) ^ 1);
                float a = 0.f;
#pragma unroll
                for (int i = 0; i < 4; ++i) {
                    const int k = k0 + 2 * i;
                    int m = t + k - 7;
                    m = (m < 0) ? -m : m;
                    const float2 pv = st[sb][m >> 1];
                    a = fmaf(pv.x, frl[k], a);
                    a = fmaf(pv.y, frh[k], a);
                }
                acc[jj] = a;
            }
            res0 = acc[0]; res1 = acc[1]; res2 = acc[2]; res3 = acc[3];
        }

        floatx4 r;
        r.x = res0 + xv.x + dq0;
        r.y = res1 + xv.y + dq1;
        r.z = res2 + xv.z + dq2;
        r.w = res3 + xv.w + dq3;
        __builtin_nontemporal_store(r, (floatx4*)(out + off));

        xv = xn; xn = xn2; cur ^= 1; sb ^= 1; off += rstride;
    }
}

extern "C" void kernel_launch(void* const* d_in, const int* in_sizes, int n_in,
                              void* d_out, int out_size, void* d_ws, size_t ws_size,
                              hipStream_t stream) {
    const float* x      = (const float*)d_in[0];
    const float* dec_lo = (const float*)d_in[1];
    const float* dec_hi = (const float*)d_in[2];
    const float* rec_lo = (const float*)d_in[3];
    const float* rec_hi = (const float*)d_in[4];
    const float* sp_c   = (const float*)d_in[5];
    const int*   sp_i   = (const int*)d_in[6];
    float* out = (float*)d_out;

    const int Brows = in_sizes[0] / D_LEN;   // 32768
    const int J     = Brows / GRID;          // 16

    wavecore_kernel<<<GRID, 256, 0, stream>>>(x, dec_lo, dec_hi, rec_lo, rec_hi,
                                              sp_c, sp_i, out, J);
}

// Round 13
// 46.282 us; speedup vs baseline: 1.0184x; 1.0184x over previous
//
#include <hip/hip_runtime.h>

// R11 structure (best: 46.5us), ONE change: hot-loop barrier is a raw
// s_barrier with lgkmcnt(0)-only fence (LDS producer->consumer), NOT
// __syncthreads (which emits s_waitcnt vmcnt(0) and drains the row-j+2
// global prefetch at every iteration). No cross-wave global communication
// exists in the loop (x read-only, out write-only), so skipping the vmcnt
// drain is safe; all LDS windows are barrier-separated (double buffers).
#define D_LEN 1024
#define K_LEN 8
#define NS    10
#define LCC   516
#define GRID  2048

typedef float floatx4 __attribute__((ext_vector_type(4)));

// LDS-only barrier: drain LDS ops, then raw s_barrier. Global loads/stores
// stay in flight (counted vmcnt waits appear only at true consumers).
#define LDS_BARRIER() do {                                   \
    asm volatile("s_waitcnt lgkmcnt(0)" ::: "memory");       \
    __builtin_amdgcn_s_barrier();                            \
} while (0)

__global__ __launch_bounds__(256) void wavecore_kernel(
    const float* __restrict__ x,
    const float* __restrict__ dec_lo, const float* __restrict__ dec_hi,
    const float* __restrict__ rec_lo, const float* __restrict__ rec_hi,
    const float* __restrict__ sp_c,   const int* __restrict__ sp_i,
    float* __restrict__ out, int J)
{
    __shared__ __align__(16) float  sx[2][D_LEN];
    __shared__ __align__(16) float2 st[2][512];

    const int tid = threadIdx.x;

    float fdl[K_LEN], fdh[K_LEN], frl[K_LEN], frh[K_LEN];
#pragma unroll
    for (int k = 0; k < K_LEN; ++k) {
        fdl[k] = dec_lo[k]; fdh[k] = dec_hi[k];
        frl[k] = rec_lo[k]; frh[k] = rec_hi[k];
    }

    // ---- inline delta: dq = rec(sparse-only pairs) for this thread's quad ----
    float dq0, dq1, dq2, dq3;
    {
        float4 z; z.x = 0.f; z.y = 0.f; z.z = 0.f; z.w = 0.f;
        ((float4*)st[0])[tid] = z;
        __syncthreads();
        if (tid < NS) {
            const int   s = sp_i[tid];
            const float v = sp_c[tid];
            if (s < 512)       st[0][s].x = v;        // distinct indices, no race
            else if (s >= LCC) st[0][s - LCC].y = v;  // lo c in [512,516) unused
        }
        __syncthreads();
        if (tid >= 2) {
            const float4 qa = ((const float4*)st[0])[tid - 2];
            const float4 qb = ((const float4*)st[0])[tid - 1];
            const float4 qc = ((const float4*)st[0])[tid];
            const float p0l = qa.z, p0h = qa.w;
            const float p1l = qb.x, p1h = qb.y;
            const float p2l = qb.z, p2h = qb.w;
            const float p3l = qc.x, p3h = qc.y;
            const float p4l = qc.z, p4h = qc.w;
            dq0 = p0l*frl[1] + p0h*frh[1] + p1l*frl[3] + p1h*frh[3]
                + p2l*frl[5] + p2h*frh[5] + p3l*frl[7] + p3h*frh[7];
            dq1 = p0l*frl[0] + p0h*frh[0] + p1l*frl[2] + p1h*frh[2]
                + p2l*frl[4] + p2h*frh[4] + p3l*frl[6] + p3h*frh[6];
            dq2 = p1l*frl[1] + p1h*frh[1] + p2l*frl[3] + p2h*frh[3]
                + p3l*frl[5] + p3h*frh[5] + p4l*frl[7] + p4h*frh[7];
            dq3 = p1l*frl[0] + p1h*frh[0] + p2l*frl[2] + p2h*frh[2]
                + p3l*frl[4] + p3h*frh[4] + p4l*frl[6] + p4h*frh[6];
        } else {
            float acc[4];
#pragma unroll
            for (int j = 0; j < 4; ++j) {
                const int t  = 4 * tid + j;
                const int k0 = ((j & 1) ^ 1);
                float a = 0.f;
#pragma unroll
                for (int i = 0; i < 4; ++i) {
                    const int k = k0 + 2 * i;
                    int m = t + k - 7;
                    m = (m < 0) ? -m : m;
                    const float2 pv = st[0][m >> 1];
                    a = fmaf(pv.x, frl[k], a);
                    a = fmaf(pv.y, frh[k], a);
                }
                acc[j] = a;
            }
            dq0 = acc[0]; dq1 = acc[1]; dq2 = acc[2]; dq3 = acc[3];
        }
        __syncthreads();   // st[0] free for reuse
    }

    // ---- prologue: row0 -> regs+sx[0]; row1 -> xn ----
    size_t off = (size_t)blockIdx.x * D_LEN + 4 * (size_t)tid;
    const size_t rstride = (size_t)GRID * D_LEN;
    float4 xv = *(const float4*)(x + off);
    ((float4*)sx[0])[tid] = xv;
    float4 xn = *(const float4*)(x + off + rstride);   // J >= 2
    __syncthreads();                                   // sx[0] ready

    int cur = 0, sb = 0;
#pragma unroll 1
    for (int j = 0; j < J; ++j) {
        // prefetch row j+2 (survives the LDS-only barrier; consumed by the
        // ds_write staging one full iteration later -> counted vmcnt wait)
        float4 xn2;
        if (j + 2 < J) xn2 = *(const float4*)(x + off + 2 * rstride);

        // ---- phase 2 on sx[cur] + own regs -> st[sb] ----
        const float* sxc = sx[cur];
        float lo0 = 0.f, hi0 = 0.f, lo1 = 0.f, hi1 = 0.f;
        if (tid >= 2) {
            const float4 wa = ((const float4*)sxc)[tid - 2];
            const float4 wb = ((const float4*)sxc)[tid - 1];
            const float w[12] = { wa.x, wa.y, wa.z, wa.w,
                                  wb.x, wb.y, wb.z, wb.w,
                                  xv.x, xv.y, xv.z, xv.w };
#pragma unroll
            for (int jj = 0; jj < K_LEN; ++jj) {
                const float v0 = w[8  - jj];
                const float v1 = w[10 - jj];
                lo0 = fmaf(v0, fdl[jj], lo0);
                hi0 = fmaf(v0, fdh[jj], hi0);
                lo1 = fmaf(v1, fdl[jj], lo1);
                hi1 = fmaf(v1, fdh[jj], hi1);
            }
        } else {
#pragma unroll
            for (int q = 0; q < 2; ++q) {
                const int c = 2 * tid + q;
                float aL = 0.f, aH = 0.f;
#pragma unroll
                for (int jj = 0; jj < K_LEN; ++jj) {
                    int m = 2 * c - jj;
                    m = (m < 0) ? -m : m;
                    const float v = sxc[m];
                    aL = fmaf(v, fdl[jj], aL);
                    aH = fmaf(v, fdh[jj], aH);
                }
                if (q == 0) { lo0 = aL; hi0 = aH; }
                else        { lo1 = aL; hi1 = aH; }
            }
        }
        {
            float4 pr; pr.x = lo0; pr.y = hi0; pr.z = lo1; pr.w = hi1;
            ((float4*)st[sb])[tid] = pr;
        }
        // stage row j+1 into alternate x-buffer (vmcnt-waits on its own load)
        if (j + 1 < J) ((float4*)sx[cur ^ 1])[tid] = xn;

        LDS_BARRIER();   // lgkmcnt(0) + s_barrier; NO vmcnt drain

        // ---- phase 3 from st[sb] + own pair regs; nt store ----
        float res0, res1, res2, res3;
        if (tid >= 2) {
            const float4 qa = ((const float4*)st[sb])[tid - 2];
            const float4 qb = ((const float4*)st[sb])[tid - 1];
            const float p0l = qa.z, p0h = qa.w;
            const float p1l = qb.x, p1h = qb.y;
            const float p2l = qb.z, p2h = qb.w;
            const float p3l = lo0,  p3h = hi0;
            const float p4l = lo1,  p4h = hi1;
            res0 = p0l*frl[1] + p0h*frh[1] + p1l*frl[3] + p1h*frh[3]
                 + p2l*frl[5] + p2h*frh[5] + p3l*frl[7] + p3h*frh[7];
            res1 = p0l*frl[0] + p0h*frh[0] + p1l*frl[2] + p1h*frh[2]
                 + p2l*frl[4] + p2h*frh[4] + p3l*frl[6] + p3h*frh[6];
            res2 = p1l*frl[1] + p1h*frh[1] + p2l*frl[3] + p2h*frh[3]
                 + p3l*frl[5] + p3h*frh[5] + p4l*frl[7] + p4h*frh[7];
            res3 = p1l*frl[0] + p1h*frh[0] + p2l*frl[2] + p2h*frh[2]
                 + p3l*frl[4] + p3h*frh[4] + p4l*frl[6] + p4h*frh[6];
        } else {
            float acc[4];
#pragma unroll
            for (int jj = 0; jj < 4; ++jj) {
                const int t  = 4 * tid + jj;
                const int k0 = ((jj & 1) ^ 1);
                float a = 0.f;
#pragma unroll
                for (int i = 0; i < 4; ++i) {
                    const int k = k0 + 2 * i;
                    int m = t + k - 7;
                    m = (m < 0) ? -m : m;
                    const float2 pv = st[sb][m >> 1];
                    a = fmaf(pv.x, frl[k], a);
                    a = fmaf(pv.y, frh[k], a);
                }
                acc[jj] = a;
            }
            res0 = acc[0]; res1 = acc[1]; res2 = acc[2]; res3 = acc[3];
        }

        floatx4 r;
        r.x = res0 + xv.x + dq0;
        r.y = res1 + xv.y + dq1;
        r.z = res2 + xv.z + dq2;
        r.w = res3 + xv.w + dq3;
        __builtin_nontemporal_store(r, (floatx4*)(out + off));

        xv = xn; xn = xn2; cur ^= 1; sb ^= 1; off += rstride;
    }
}

extern "C" void kernel_launch(void* const* d_in, const int* in_sizes, int n_in,
                              void* d_out, int out_size, void* d_ws, size_t ws_size,
                              hipStream_t stream) {
    const float* x      = (const float*)d_in[0];
    const float* dec_lo = (const float*)d_in[1];
    const float* dec_hi = (const float*)d_in[2];
    const float* rec_lo = (const float*)d_in[3];
    const float* rec_hi = (const float*)d_in[4];
    const float* sp_c   = (const float*)d_in[5];
    const int*   sp_i   = (const int*)d_in[6];
    float* out = (float*)d_out;

    const int Brows = in_sizes[0] / D_LEN;   // 32768
    const int J     = Brows / GRID;          // 16

    wavecore_kernel<<<GRID, 256, 0, stream>>>(x, dec_lo, dec_hi, rec_lo, rec_hi,
                                              sp_c, sp_i, out, J);
}